// Round 1
// baseline (2804.592 us; speedup 1.0000x reference)
//
#include <hip/hip_runtime.h>
#include <hip/hip_bf16.h>
#include <math.h>

// Problem constants (from setup_inputs): B=2, S=2048 -> M=4096 tokens,
// K=4096, N=11008, groupsize=128.
static constexpr int M  = 4096;
static constexpr int K  = 4096;   // hidden dim (gate/up reduction, down output)
static constexpr int NN = 11008;  // intermediate dim (gate/up output, down reduction)

typedef __bf16 bf16;
typedef __bf16 bf16x8 __attribute__((ext_vector_type(8)));
typedef float  f32x4  __attribute__((ext_vector_type(4)));

// LDS row stride for 32-k tiles: pad 32 -> 40 elems (80 B, still 16B-aligned
// per row so ds_read_b128 works; breaks the 64B power-of-2 bank stride).
static constexpr int LDK = 40;

// ---------------------------------------------------------------------------
// Kernel 1: h = silu(x @ Wg) * (x @ Wu), Wg/Wu dequantized GPTQ int4 on the fly.
// Tile: 128(M) x 128(N), BK=32. 256 threads = 4 waves in 2x2, each wave does
// 64x64 via 4x4 grid of 16x16x32 bf16 MFMAs (for both gate and up).
// ---------------------------------------------------------------------------
__global__ __launch_bounds__(256) void gateup_kernel(
    const float* __restrict__ x,        // (M, K) fp32
    const int*   __restrict__ gqw,      // (K/8, NN)
    const float* __restrict__ gsc,      // (K/128, NN)
    const int*   __restrict__ gqz,      // (K/128, NN/8)
    const int*   __restrict__ uqw,
    const float* __restrict__ usc,
    const int*   __restrict__ uqz,
    bf16*        __restrict__ h)        // (M, NN) bf16
{
    __shared__ bf16 As[128][LDK];
    __shared__ bf16 Bg[128][LDK];
    __shared__ bf16 Bu[128][LDK];

    const int tid    = threadIdx.x;
    const int m_base = blockIdx.y * 128;
    const int n_base = blockIdx.x * 128;

    const int lane = tid & 63;
    const int wave = tid >> 6;
    const int wm   = (wave >> 1) * 64;
    const int wn   = (wave & 1) * 64;
    const int quad = lane >> 4;
    const int lr   = lane & 15;

    f32x4 accg[4][4];
    f32x4 accu[4][4];
#pragma unroll
    for (int i = 0; i < 4; ++i)
#pragma unroll
        for (int j = 0; j < 4; ++j) {
            accg[i][j] = (f32x4){0.f, 0.f, 0.f, 0.f};
            accu[i][j] = (f32x4){0.f, 0.f, 0.f, 0.f};
        }

    const int nn  = tid & 127;   // B-staging column within tile
    const int kr0 = tid >> 7;    // 0/1 -> handles qweight rows kr0 and kr0+2

    for (int k0 = 0; k0 < K; k0 += 32) {
        // ---- stage A: x[m_base..+128][k0..+32] fp32 -> bf16 LDS ----
#pragma unroll
        for (int r = 0; r < 2; ++r) {
            int idx = r * 256 + tid;       // 0..511
            int m   = idx >> 2;
            int kg  = (idx & 3) * 8;
            const float* src = x + (size_t)(m_base + m) * K + k0 + kg;
            float4 f0 = *(const float4*)src;
            float4 f1 = *(const float4*)(src + 4);
            bf16x8 v;
            v[0] = (bf16)f0.x; v[1] = (bf16)f0.y; v[2] = (bf16)f0.z; v[3] = (bf16)f0.w;
            v[4] = (bf16)f1.x; v[5] = (bf16)f1.y; v[6] = (bf16)f1.z; v[7] = (bf16)f1.w;
            *(bf16x8*)&As[m][kg] = v;
        }

        // ---- stage B: dequant gate/up int4 -> bf16 LDS (transposed: [n][k]) ----
        const int g  = k0 >> 7;            // group index (gs=128)
        const int gn = n_base + nn;
        float sg = gsc[(size_t)g * NN + gn];
        float su = usc[(size_t)g * NN + gn];
        int zqg = gqz[(size_t)g * (NN / 8) + (gn >> 3)];
        int zqu = uqz[(size_t)g * (NN / 8) + (gn >> 3)];
        int sh  = (nn & 7) * 4;
        float zsg = (float)(((zqg >> sh) & 15) + 1) * sg;
        float zsu = (float)(((zqu >> sh) & 15) + 1) * su;

#pragma unroll
        for (int rr = 0; rr < 2; ++rr) {
            int kr = kr0 + rr * 2;         // 0..3
            int qg = gqw[(size_t)(k0 / 8 + kr) * NN + gn];
            int qu = uqw[(size_t)(k0 / 8 + kr) * NN + gn];
            bf16x8 vg, vu;
#pragma unroll
            for (int j = 0; j < 8; ++j) {
                int wg = (qg >> (4 * j)) & 15;
                int wu = (qu >> (4 * j)) & 15;
                vg[j] = (bf16)((float)wg * sg - zsg);
                vu[j] = (bf16)((float)wu * su - zsu);
            }
            *(bf16x8*)&Bg[nn][kr * 8] = vg;
            *(bf16x8*)&Bu[nn][kr * 8] = vu;
        }

        __syncthreads();

        // ---- MFMA ----
        bf16x8 af[4], bgf[4], buf_[4];
#pragma unroll
        for (int t = 0; t < 4; ++t) af[t]   = *(const bf16x8*)&As[wm + t * 16 + lr][quad * 8];
#pragma unroll
        for (int t = 0; t < 4; ++t) bgf[t]  = *(const bf16x8*)&Bg[wn + t * 16 + lr][quad * 8];
#pragma unroll
        for (int t = 0; t < 4; ++t) buf_[t] = *(const bf16x8*)&Bu[wn + t * 16 + lr][quad * 8];

#pragma unroll
        for (int mt = 0; mt < 4; ++mt)
#pragma unroll
            for (int nt = 0; nt < 4; ++nt) {
                accg[mt][nt] = __builtin_amdgcn_mfma_f32_16x16x32_bf16(af[mt], bgf[nt],  accg[mt][nt], 0, 0, 0);
                accu[mt][nt] = __builtin_amdgcn_mfma_f32_16x16x32_bf16(af[mt], buf_[nt], accu[mt][nt], 0, 0, 0);
            }

        __syncthreads();
    }

    // ---- epilogue: silu(g)*u -> h (bf16) ----
#pragma unroll
    for (int mt = 0; mt < 4; ++mt)
#pragma unroll
        for (int nt = 0; nt < 4; ++nt)
#pragma unroll
            for (int r = 0; r < 4; ++r) {
                int m = m_base + wm + mt * 16 + quad * 4 + r;
                int n = n_base + wn + nt * 16 + lr;
                float gv = accg[mt][nt][r];
                float uv = accu[mt][nt][r];
                float hv = (gv / (1.0f + __expf(-gv))) * uv;
                h[(size_t)m * NN + n] = (bf16)hv;
            }
}

// ---------------------------------------------------------------------------
// Kernel 2: out = h @ Wd (Wd dequantized on the fly). Reduction over NN.
// ---------------------------------------------------------------------------
__global__ __launch_bounds__(256) void down_kernel(
    const bf16*  __restrict__ h,        // (M, NN) bf16
    const int*   __restrict__ dqw,      // (NN/8, K)
    const float* __restrict__ dsc,      // (NN/128, K)
    const int*   __restrict__ dqz,      // (NN/128, K/8)
    float*       __restrict__ out)      // (M, K) fp32
{
    __shared__ bf16 As[128][LDK];
    __shared__ bf16 Bs[128][LDK];

    const int tid    = threadIdx.x;
    const int m_base = blockIdx.y * 128;
    const int c_base = blockIdx.x * 128;  // output column base

    const int lane = tid & 63;
    const int wave = tid >> 6;
    const int wm   = (wave >> 1) * 64;
    const int wn   = (wave & 1) * 64;
    const int quad = lane >> 4;
    const int lr   = lane & 15;

    f32x4 acc[4][4];
#pragma unroll
    for (int i = 0; i < 4; ++i)
#pragma unroll
        for (int j = 0; j < 4; ++j) acc[i][j] = (f32x4){0.f, 0.f, 0.f, 0.f};

    const int cc  = tid & 127;
    const int kr0 = tid >> 7;

    for (int n0 = 0; n0 < NN; n0 += 32) {
        // ---- stage A: h[m_base..+128][n0..+32] bf16 (direct 16B copies) ----
#pragma unroll
        for (int r = 0; r < 2; ++r) {
            int idx = r * 256 + tid;
            int m   = idx >> 2;
            int kg  = (idx & 3) * 8;
            *(bf16x8*)&As[m][kg] =
                *(const bf16x8*)(h + (size_t)(m_base + m) * NN + n0 + kg);
        }

        // ---- stage B: dequant down int4 ----
        const int g  = n0 >> 7;
        const int gc = c_base + cc;
        float s  = dsc[(size_t)g * K + gc];
        int  zq  = dqz[(size_t)g * (K / 8) + (gc >> 3)];
        int  sh  = (cc & 7) * 4;
        float zs = (float)(((zq >> sh) & 15) + 1) * s;

#pragma unroll
        for (int rr = 0; rr < 2; ++rr) {
            int kr = kr0 + rr * 2;
            int q  = dqw[(size_t)(n0 / 8 + kr) * K + gc];
            bf16x8 v;
#pragma unroll
            for (int j = 0; j < 8; ++j) {
                int w = (q >> (4 * j)) & 15;
                v[j] = (bf16)((float)w * s - zs);
            }
            *(bf16x8*)&Bs[cc][kr * 8] = v;
        }

        __syncthreads();

        bf16x8 af[4], bf[4];
#pragma unroll
        for (int t = 0; t < 4; ++t) af[t] = *(const bf16x8*)&As[wm + t * 16 + lr][quad * 8];
#pragma unroll
        for (int t = 0; t < 4; ++t) bf[t] = *(const bf16x8*)&Bs[wn + t * 16 + lr][quad * 8];

#pragma unroll
        for (int mt = 0; mt < 4; ++mt)
#pragma unroll
            for (int nt = 0; nt < 4; ++nt)
                acc[mt][nt] = __builtin_amdgcn_mfma_f32_16x16x32_bf16(af[mt], bf[nt], acc[mt][nt], 0, 0, 0);

        __syncthreads();
    }

#pragma unroll
    for (int mt = 0; mt < 4; ++mt)
#pragma unroll
        for (int nt = 0; nt < 4; ++nt)
#pragma unroll
            for (int r = 0; r < 4; ++r) {
                int m = m_base + wm + mt * 16 + quad * 4 + r;
                int c = c_base + wn + nt * 16 + lr;
                out[(size_t)m * K + c] = acc[mt][nt][r];
            }
}

extern "C" void kernel_launch(void* const* d_in, const int* in_sizes, int n_in,
                              void* d_out, int out_size, void* d_ws, size_t ws_size,
                              hipStream_t stream) {
    const float* x   = (const float*)d_in[0];
    const int*   gqw = (const int*)d_in[1];
    const float* gsc = (const float*)d_in[2];
    const int*   gqz = (const int*)d_in[3];
    const int*   uqw = (const int*)d_in[4];
    const float* usc = (const float*)d_in[5];
    const int*   uqz = (const int*)d_in[6];
    const int*   dqw = (const int*)d_in[7];
    const float* dsc = (const float*)d_in[8];
    const int*   dqz = (const int*)d_in[9];

    bf16*  h   = (bf16*)d_ws;            // (M, NN) bf16 = ~90 MB
    float* out = (float*)d_out;          // (M, K) fp32

    dim3 g1(NN / 128, M / 128);          // 86 x 32
    gateup_kernel<<<g1, 256, 0, stream>>>(x, gqw, gsc, gqz, uqw, usc, uqz, h);

    dim3 g2(K / 128, M / 128);           // 32 x 32
    down_kernel<<<g2, 256, 0, stream>>>(h, dqw, dsc, dqz, out);
}

// Round 3
// 2383.824 us; speedup vs baseline: 1.1765x; 1.1765x over previous
//
#include <hip/hip_runtime.h>
#include <hip/hip_bf16.h>

// B=2, S=2048 -> M=4096 tokens, K=4096, NN=11008, groupsize=128.
static constexpr int M  = 4096;
static constexpr int K  = 4096;
static constexpr int NN = 11008;

typedef _Float16 f16;
typedef _Float16 f16x2 __attribute__((ext_vector_type(2)));
typedef _Float16 f16x8 __attribute__((ext_vector_type(8)));
typedef float    f32x4 __attribute__((ext_vector_type(4)));

// LDS row: 32 data halves + 8 pad = 40 (80 B, 16B-aligned rows).
static constexpr int LDK = 40;

// GPTQ nibble j of an int32 covers k = 8r+j. The magic unpack produces the
// interleaved order: position p holds actual k-offset (p>>1) + (p&1)*4,
// i.e. [0,4,1,5,2,6,3,7]. A-side data (x, h) is pre-permuted to match, so
// dot products are over a consistent permutation of k.
//
// Numerics: 0x6400|w bitcasts to fp16 (1024+w) EXACTLY; zc = (1025+z) is an
// integer <= 1040, also exact in fp16; their pk_add difference (w-z-1) is an
// exact small integer. Single rounding happens only at the final pk_mul by s
// (rel err 2^-12 at the weight's own magnitude). No large-magnitude constant
// is ever rounded (that was round-2's 80-absmax failure).
union dq_u { f16x2 h[4]; f16x8 v; };

__device__ __forceinline__ f16x8 dq8(unsigned q, f16x2 s2, f16x2 zc2) {
    dq_u u;
    unsigned t0 = ( q         & 0x000F000Fu) | 0x64006400u;  // (w0, w4)+1024
    unsigned t1 = ((q >> 4)   & 0x000F000Fu) | 0x64006400u;  // (w1, w5)+1024
    unsigned t2 = ((q >> 8)   & 0x000F000Fu) | 0x64006400u;  // (w2, w6)+1024
    unsigned t3 = ((q >> 12)  & 0x000F000Fu) | 0x64006400u;  // (w3, w7)+1024
    u.h[0] = (__builtin_bit_cast(f16x2, t0) - zc2) * s2;     // exact sub, 1 rounding
    u.h[1] = (__builtin_bit_cast(f16x2, t1) - zc2) * s2;
    u.h[2] = (__builtin_bit_cast(f16x2, t2) - zc2) * s2;
    u.h[3] = (__builtin_bit_cast(f16x2, t3) - zc2) * s2;
    return u.v;
}

// ---------------------------------------------------------------------------
// Pre-pass: x fp32 -> fp16, permuted within each 8 along K to match dq8 order.
// ---------------------------------------------------------------------------
__global__ __launch_bounds__(256) void convert_x_kernel(
    const float* __restrict__ x, f16* __restrict__ xp)
{
    size_t i = ((size_t)blockIdx.x * 256 + threadIdx.x) * 8;
    float4 f0 = *(const float4*)(x + i);
    float4 f1 = *(const float4*)(x + i + 4);
    f16x8 v;
    v[0] = (f16)f0.x; v[1] = (f16)f1.x;   // k0, k4
    v[2] = (f16)f0.y; v[3] = (f16)f1.y;   // k1, k5
    v[4] = (f16)f0.z; v[5] = (f16)f1.z;   // k2, k6
    v[6] = (f16)f0.w; v[7] = (f16)f1.w;   // k3, k7
    *(f16x8*)(xp + i) = v;
}

// ---------------------------------------------------------------------------
// Kernel 1: h = silu(x @ Wg) * (x @ Wu). 128x128 tile, BK=32, 4 waves,
// each wave 64x64 via 4x4 grid of 16x16x32 f16 MFMAs for BOTH matrices.
// Chunk-rotation swizzle ((c+row)&3) keeps all LDS accesses <=2-way.
// ---------------------------------------------------------------------------
__global__ __launch_bounds__(256) void gateup_kernel(
    const f16*   __restrict__ xp,       // (M, K) fp16, permuted within 8
    const int*   __restrict__ gqw,      // (K/8, NN)
    const float* __restrict__ gsc,      // (K/128, NN)
    const int*   __restrict__ gqz,      // (K/128, NN/8)
    const int*   __restrict__ uqw,
    const float* __restrict__ usc,
    const int*   __restrict__ uqz,
    f16*         __restrict__ h)        // (M, NN) fp16, permuted within 8 along NN
{
    __shared__ f16 As[128][LDK];
    __shared__ f16 Bg[128][LDK];
    __shared__ f16 Bu[128][LDK];

    const int tid    = threadIdx.x;
    const int m_base = blockIdx.y * 128;
    const int n_base = blockIdx.x * 128;

    const int lane = tid & 63;
    const int wave = tid >> 6;
    const int wm   = (wave >> 1) * 64;
    const int wn   = (wave & 1) * 64;
    const int quad = lane >> 4;
    const int lr   = lane & 15;

    f32x4 accg[4][4], accu[4][4];
#pragma unroll
    for (int i = 0; i < 4; ++i)
#pragma unroll
        for (int j = 0; j < 4; ++j) {
            accg[i][j] = (f32x4){0.f, 0.f, 0.f, 0.f};
            accu[i][j] = (f32x4){0.f, 0.f, 0.f, 0.f};
        }

    const int nn  = tid & 127;   // B-staging column within tile
    const int kr0 = tid >> 7;    // handles qweight rows kr0, kr0+2
    const int gn  = n_base + nn;
    const int sh  = (nn & 7) * 4;
    const int am  = tid >> 2;    // A-staging row (r*64 + am)
    const int ac  = tid & 3;     // A-staging chunk

    for (int g = 0; g < 32; ++g) {
        // group constants (hoisted over 4 k-iterations)
        float sgf = gsc[(size_t)g * NN + gn];
        float suf = usc[(size_t)g * NN + gn];
        int zg = (gqz[(size_t)g * (NN / 8) + (gn >> 3)] >> sh) & 15;
        int zu = (uqz[(size_t)g * (NN / 8) + (gn >> 3)] >> sh) & 15;
        f16 sgh = (f16)sgf, suh = (f16)suf;
        f16 zcg = (f16)(float)(1025 + zg);   // exact integer in fp16
        f16 zcu = (f16)(float)(1025 + zu);
        f16x2 s2g = {sgh, sgh}, zc2g = {zcg, zcg};
        f16x2 s2u = {suh, suh}, zc2u = {zcu, zcu};

        for (int kk = 0; kk < 4; ++kk) {
            const int k0 = g * 128 + kk * 32;

            // ---- stage A: 16B copies, no conversion ----
#pragma unroll
            for (int r = 0; r < 2; ++r) {
                int m = r * 64 + am;
                f16x8 v = *(const f16x8*)(xp + (size_t)(m_base + m) * K + k0 + ac * 8);
                *(f16x8*)&As[m][((ac + m) & 3) * 8] = v;
            }

            // ---- stage B: magic fp16 dequant ----
#pragma unroll
            for (int rr = 0; rr < 2; ++rr) {
                int kr = kr0 + rr * 2;
                unsigned qg = (unsigned)gqw[(size_t)(k0 / 8 + kr) * NN + gn];
                unsigned qu = (unsigned)uqw[(size_t)(k0 / 8 + kr) * NN + gn];
                *(f16x8*)&Bg[nn][((kr + nn) & 3) * 8] = dq8(qg, s2g, zc2g);
                *(f16x8*)&Bu[nn][((kr + nn) & 3) * 8] = dq8(qu, s2u, zc2u);
            }

            __syncthreads();

            f16x8 af[4], bg[4], bu[4];
#pragma unroll
            for (int t = 0; t < 4; ++t) {
                int row = wm + t * 16 + lr;
                af[t] = *(const f16x8*)&As[row][((quad + row) & 3) * 8];
            }
#pragma unroll
            for (int t = 0; t < 4; ++t) {
                int row = wn + t * 16 + lr;
                bg[t] = *(const f16x8*)&Bg[row][((quad + row) & 3) * 8];
                bu[t] = *(const f16x8*)&Bu[row][((quad + row) & 3) * 8];
            }

#pragma unroll
            for (int mt = 0; mt < 4; ++mt)
#pragma unroll
                for (int nt = 0; nt < 4; ++nt) {
                    accg[mt][nt] = __builtin_amdgcn_mfma_f32_16x16x32_f16(af[mt], bg[nt], accg[mt][nt], 0, 0, 0);
                    accu[mt][nt] = __builtin_amdgcn_mfma_f32_16x16x32_f16(af[mt], bu[nt], accu[mt][nt], 0, 0, 0);
                }

            __syncthreads();
        }
    }

    // ---- epilogue: silu(g)*u -> h (fp16), columns permuted within 8 ----
#pragma unroll
    for (int mt = 0; mt < 4; ++mt)
#pragma unroll
        for (int nt = 0; nt < 4; ++nt)
#pragma unroll
            for (int r = 0; r < 4; ++r) {
                int m = m_base + wm + mt * 16 + quad * 4 + r;
                int n = n_base + wn + nt * 16 + lr;
                int np = (n & ~7) | (((n & 3) << 1) | ((n >> 2) & 1));
                float gv = accg[mt][nt][r];
                float uv = accu[mt][nt][r];
                float hv = (gv / (1.0f + __expf(-gv))) * uv;
                h[(size_t)m * NN + np] = (f16)hv;
            }
}

// ---------------------------------------------------------------------------
// Kernel 2: out = h @ Wd. Reduction over NN (permuted order, consistent on
// both sides). Output columns along K are natural order.
// ---------------------------------------------------------------------------
__global__ __launch_bounds__(256) void down_kernel(
    const f16*   __restrict__ h,        // (M, NN) fp16, permuted within 8
    const int*   __restrict__ dqw,      // (NN/8, K)
    const float* __restrict__ dsc,      // (NN/128, K)
    const int*   __restrict__ dqz,      // (NN/128, K/8)
    float*       __restrict__ out)      // (M, K) fp32
{
    __shared__ f16 As[128][LDK];
    __shared__ f16 Bs[128][LDK];

    const int tid    = threadIdx.x;
    const int m_base = blockIdx.y * 128;
    const int c_base = blockIdx.x * 128;

    const int lane = tid & 63;
    const int wave = tid >> 6;
    const int wm   = (wave >> 1) * 64;
    const int wn   = (wave & 1) * 64;
    const int quad = lane >> 4;
    const int lr   = lane & 15;

    f32x4 acc[4][4];
#pragma unroll
    for (int i = 0; i < 4; ++i)
#pragma unroll
        for (int j = 0; j < 4; ++j) acc[i][j] = (f32x4){0.f, 0.f, 0.f, 0.f};

    const int cc  = tid & 127;
    const int kr0 = tid >> 7;
    const int gc  = c_base + cc;
    const int sh  = (cc & 7) * 4;
    const int am  = tid >> 2;
    const int ac  = tid & 3;

    for (int g = 0; g < 86; ++g) {
        float sf = dsc[(size_t)g * K + gc];
        int   z  = (dqz[(size_t)g * (K / 8) + (gc >> 3)] >> sh) & 15;
        f16 shh = (f16)sf;
        f16 zch = (f16)(float)(1025 + z);
        f16x2 s2 = {shh, shh}, zc2 = {zch, zch};

        for (int kk = 0; kk < 4; ++kk) {
            const int n0 = g * 128 + kk * 32;

            // ---- stage A: h is fp16 & pre-permuted: plain 16B copies ----
#pragma unroll
            for (int r = 0; r < 2; ++r) {
                int m = r * 64 + am;
                f16x8 v = *(const f16x8*)(h + (size_t)(m_base + m) * NN + n0 + ac * 8);
                *(f16x8*)&As[m][((ac + m) & 3) * 8] = v;
            }

            // ---- stage B: dequant down int4 ----
#pragma unroll
            for (int rr = 0; rr < 2; ++rr) {
                int kr = kr0 + rr * 2;
                unsigned q = (unsigned)dqw[(size_t)(n0 / 8 + kr) * K + gc];
                *(f16x8*)&Bs[cc][((kr + cc) & 3) * 8] = dq8(q, s2, zc2);
            }

            __syncthreads();

            f16x8 af[4], bf[4];
#pragma unroll
            for (int t = 0; t < 4; ++t) {
                int row = wm + t * 16 + lr;
                af[t] = *(const f16x8*)&As[row][((quad + row) & 3) * 8];
            }
#pragma unroll
            for (int t = 0; t < 4; ++t) {
                int row = wn + t * 16 + lr;
                bf[t] = *(const f16x8*)&Bs[row][((quad + row) & 3) * 8];
            }

#pragma unroll
            for (int mt = 0; mt < 4; ++mt)
#pragma unroll
                for (int nt = 0; nt < 4; ++nt)
                    acc[mt][nt] = __builtin_amdgcn_mfma_f32_16x16x32_f16(af[mt], bf[nt], acc[mt][nt], 0, 0, 0);

            __syncthreads();
        }
    }

#pragma unroll
    for (int mt = 0; mt < 4; ++mt)
#pragma unroll
        for (int nt = 0; nt < 4; ++nt)
#pragma unroll
            for (int r = 0; r < 4; ++r) {
                int m = m_base + wm + mt * 16 + quad * 4 + r;
                int c = c_base + wn + nt * 16 + lr;
                out[(size_t)m * K + c] = acc[mt][nt][r];
            }
}

extern "C" void kernel_launch(void* const* d_in, const int* in_sizes, int n_in,
                              void* d_out, int out_size, void* d_ws, size_t ws_size,
                              hipStream_t stream) {
    const float* x   = (const float*)d_in[0];
    const int*   gqw = (const int*)d_in[1];
    const float* gsc = (const float*)d_in[2];
    const int*   gqz = (const int*)d_in[3];
    const int*   uqw = (const int*)d_in[4];
    const float* usc = (const float*)d_in[5];
    const int*   uqz = (const int*)d_in[6];
    const int*   dqw = (const int*)d_in[7];
    const float* dsc = (const float*)d_in[8];
    const int*   dqz = (const int*)d_in[9];

    f16*   h   = (f16*)d_ws;                                   // 90.2 MB
    f16*   xp  = (f16*)((char*)d_ws + (size_t)M * NN * 2);     // +33.6 MB
    float* out = (float*)d_out;

    convert_x_kernel<<<(M * K / 8) / 256, 256, 0, stream>>>(x, xp);

    dim3 g1(NN / 128, M / 128);          // 86 x 32
    gateup_kernel<<<g1, 256, 0, stream>>>(xp, gqw, gsc, gqz, uqw, usc, uqz, h);

    dim3 g2(K / 128, M / 128);           // 32 x 32
    down_kernel<<<g2, 256, 0, stream>>>(h, dqw, dsc, dqz, out);
}